// Round 3
// baseline (495.521 us; speedup 1.0000x reference)
//
#include <hip/hip_runtime.h>

// MHA forward: x[4,2048,1024] f32, W_QKV[3072,1024] f32, W_O[1024,1024] f32,
// pos[2048] i32 -> out[4,2048,1024] f32.
// Pipeline: cast->bf16 | QKV GEMM (MFMA) | RoPE repack | flash attn (MFMA) | out GEMM.

typedef __attribute__((ext_vector_type(4))) float          f32x4;
typedef __attribute__((ext_vector_type(8))) __bf16         bf16x8;
typedef __attribute__((ext_vector_type(8))) unsigned short u16x8;
typedef __attribute__((ext_vector_type(4))) unsigned short u16x4;

__device__ __forceinline__ unsigned short f2bf(float f) {
  unsigned int u = __builtin_bit_cast(unsigned int, f);
  u = (u + 0x7fffu + ((u >> 16) & 1u)) >> 16;
  return (unsigned short)u;
}
__device__ __forceinline__ float bf2f(unsigned short b) {
  return __builtin_bit_cast(float, ((unsigned int)b) << 16);
}
__device__ __forceinline__ void gload_lds16(const void* g, void* l) {
  __builtin_amdgcn_global_load_lds((const __attribute__((address_space(1))) void*)g,
                                   (__attribute__((address_space(3))) void*)l, 16, 0, 0);
}

// ---------------- cast f32 -> bf16 ----------------
__global__ void cast_f32_bf16_k(const float* __restrict__ in, unsigned short* __restrict__ out, int n) {
  int i = (blockIdx.x * blockDim.x + threadIdx.x) * 4;
  const int stride = gridDim.x * blockDim.x * 4;
  for (; i < n; i += stride) {
    float4 v = *(const float4*)(in + i);
    u16x4 o = { f2bf(v.x), f2bf(v.y), f2bf(v.z), f2bf(v.w) };
    *(u16x4*)(out + i) = o;
  }
}

// ---------------- NT GEMM: C[M][N] = A[M][K] * B[N][K]^T ----------------
// 128x128 tile, BK=64, 256 threads = 4 waves (2x2 of 64x64), 16x16x32 bf16 MFMA.
template <typename OutT>
__global__ __launch_bounds__(256) void gemm_bf16_nt(
    const unsigned short* __restrict__ A,
    const unsigned short* __restrict__ B,
    OutT* __restrict__ C,
    int M, int N, int K) {
  __shared__ unsigned short As[128 * 64];
  __shared__ unsigned short Bs[128 * 64];
  const int tid  = threadIdx.x;
  const int w    = tid >> 6;
  const int lane = tid & 63;
  const int l15  = lane & 15, l4 = lane >> 4;
  const int row0 = blockIdx.y * 128, col0 = blockIdx.x * 128;
  const int wrb  = (w >> 1) * 64, wcb = (w & 1) * 64;

  f32x4 acc[4][4];
  const f32x4 z = {0.f, 0.f, 0.f, 0.f};
#pragma unroll
  for (int m = 0; m < 4; ++m)
#pragma unroll
    for (int n = 0; n < 4; ++n) acc[m][n] = z;

  const int srow = w * 32 + (lane >> 3);  // + p*8 below
  const int scol = (lane & 7) * 8;

  for (int k0 = 0; k0 < K; k0 += 64) {
#pragma unroll
    for (int p = 0; p < 4; ++p) {
      gload_lds16(&A[(size_t)(row0 + srow + p * 8) * K + k0 + scol], &As[(w * 32 + p * 8) * 64]);
      gload_lds16(&B[(size_t)(col0 + srow + p * 8) * K + k0 + scol], &Bs[(w * 32 + p * 8) * 64]);
    }
    __syncthreads();
#pragma unroll
    for (int ks = 0; ks < 2; ++ks) {
      bf16x8 af[4], bfr[4];
#pragma unroll
      for (int m = 0; m < 4; ++m)
        af[m] = *(const bf16x8*)&As[(wrb + m * 16 + l15) * 64 + ks * 32 + l4 * 8];
#pragma unroll
      for (int n = 0; n < 4; ++n)
        bfr[n] = *(const bf16x8*)&Bs[(wcb + n * 16 + l15) * 64 + ks * 32 + l4 * 8];
#pragma unroll
      for (int m = 0; m < 4; ++m)
#pragma unroll
        for (int n = 0; n < 4; ++n)
          acc[m][n] = __builtin_amdgcn_mfma_f32_16x16x32_bf16(af[m], bfr[n], acc[m][n], 0, 0, 0);
    }
    __syncthreads();
  }
#pragma unroll
  for (int m = 0; m < 4; ++m) {
    const int row = row0 + wrb + m * 16 + l4 * 4;
#pragma unroll
    for (int n = 0; n < 4; ++n) {
      const int col = col0 + wcb + n * 16 + l15;
#pragma unroll
      for (int r = 0; r < 4; ++r) {
        float v = acc[m][n][r];
        if constexpr (sizeof(OutT) == 2)
          C[(size_t)(row + r) * N + col] = f2bf(v);
        else
          C[(size_t)(row + r) * N + col] = v;
      }
    }
  }
}

// ---------------- RoPE + repack qkv[B*S][3072] -> Q/K/V [B*H][S][64] ----------------
__global__ __launch_bounds__(512) void rope_repack(
    const unsigned short* __restrict__ qkv,
    const int* __restrict__ pos,
    unsigned short* __restrict__ Qr,
    unsigned short* __restrict__ Kr,
    unsigned short* __restrict__ Vr) {
  const int bs = blockIdx.x;          // b*2048 + s
  const int b  = bs >> 11, s = bs & 2047;
  const int t  = threadIdx.x;        // 512 = 16 heads * 32 pairs
  const int h  = t >> 5, kk = t & 31;
  const float p    = (float)pos[s];
  const float freq = powf(10000.0f, -(float)kk * (1.0f / 32.0f));
  float sn, c;
  sincosf(p * freq, &sn, &c);
  const unsigned short* base = qkv + (size_t)bs * 3072;
  const size_t oidx = ((size_t)(b * 16 + h) * 2048 + s) * 64 + 2 * kk;
  // Q
  float e = bf2f(base[h * 64 + 2 * kk]);
  float o = bf2f(base[h * 64 + 2 * kk + 1]);
  Qr[oidx]     = f2bf(c * e - sn * o);
  Qr[oidx + 1] = f2bf(sn * e + c * o);
  // K
  e = bf2f(base[1024 + h * 64 + 2 * kk]);
  o = bf2f(base[1024 + h * 64 + 2 * kk + 1]);
  Kr[oidx]     = f2bf(c * e - sn * o);
  Kr[oidx + 1] = f2bf(sn * e + c * o);
  // V (copy)
  Vr[oidx]     = base[2048 + h * 64 + 2 * kk];
  Vr[oidx + 1] = base[2048 + h * 64 + 2 * kk + 1];
}

// ---------------- causal flash attention ----------------
// grid (32 qtiles, 64 bh); 256 thr = 4 waves x 16 q-rows; 64-key KV tiles.
__global__ __launch_bounds__(256) void attn_fwd(
    const unsigned short* __restrict__ Qr,
    const unsigned short* __restrict__ Kr,
    const unsigned short* __restrict__ Vr,
    unsigned short* __restrict__ Out) {  // [B*S][1024]
  __shared__ unsigned short Ks[64 * 64];
  __shared__ unsigned short Vt[64 * 64];       // transposed: [d][key]
  __shared__ unsigned short Ps[4][16 * 64];    // per-wave P
  const int qt  = blockIdx.x;
  const int bh  = blockIdx.y;
  const int tid = threadIdx.x, w = tid >> 6, lane = tid & 63;
  const int l15 = lane & 15, l4 = lane >> 4;
  const size_t hbase = (size_t)bh * 2048 * 64;

  const int qrow_frag = qt * 64 + w * 16 + l15;
  bf16x8 qf[2];
  qf[0] = *(const bf16x8*)&Qr[hbase + (size_t)qrow_frag * 64 + l4 * 8];
  qf[1] = *(const bf16x8*)&Qr[hbase + (size_t)qrow_frag * 64 + 32 + l4 * 8];

  const f32x4 z = {0.f, 0.f, 0.f, 0.f};
  f32x4 accO[4];
#pragma unroll
  for (int d = 0; d < 4; ++d) accO[d] = z;
  float m_run[4], l_run[4];
#pragma unroll
  for (int r = 0; r < 4; ++r) { m_run[r] = -__builtin_inff(); l_run[r] = 0.f; }

  const int vkey = tid >> 2, vd0 = (tid & 3) * 16;

  for (int kt = 0; kt <= qt; ++kt) {
    // stage K tile (linear) via global_load_lds
#pragma unroll
    for (int p = 0; p < 2; ++p) {
      const unsigned short* gk =
          Kr + hbase + (size_t)(kt * 64 + w * 16 + p * 8 + (lane >> 3)) * 64 + (lane & 7) * 8;
      gload_lds16(gk, &Ks[(w * 16 + p * 8) * 64]);
    }
    // stage V transposed (reg round-trip, scalar LDS writes)
    {
      const unsigned short* gv = Vr + hbase + (size_t)(kt * 64 + vkey) * 64 + vd0;
      u16x8 v0 = *(const u16x8*)gv;
      u16x8 v1 = *(const u16x8*)(gv + 8);
#pragma unroll
      for (int i = 0; i < 8; ++i) Vt[(vd0 + i) * 64 + vkey] = v0[i];
#pragma unroll
      for (int i = 0; i < 8; ++i) Vt[(vd0 + 8 + i) * 64 + vkey] = v1[i];
    }
    __syncthreads();

    // S = Q K^T
    f32x4 sc[4];
#pragma unroll
    for (int cb = 0; cb < 4; ++cb) sc[cb] = z;
#pragma unroll
    for (int ks = 0; ks < 2; ++ks)
#pragma unroll
      for (int cb = 0; cb < 4; ++cb) {
        bf16x8 kb = *(const bf16x8*)&Ks[(cb * 16 + l15) * 64 + ks * 32 + l4 * 8];
        sc[cb] = __builtin_amdgcn_mfma_f32_16x16x32_bf16(qf[ks], kb, sc[cb], 0, 0, 0);
      }

    // scale + causal mask + row max
    const bool diag = (kt == qt);
    float rowmax[4];
#pragma unroll
    for (int r = 0; r < 4; ++r) rowmax[r] = -__builtin_inff();
#pragma unroll
    for (int cb = 0; cb < 4; ++cb)
#pragma unroll
      for (int r = 0; r < 4; ++r) {
        float v = sc[cb][r] * 0.125f;
        if (diag) {
          const int key = cb * 16 + l15;
          const int qr  = w * 16 + l4 * 4 + r;
          if (key > qr) v = -__builtin_inff();
        }
        sc[cb][r] = v;
        rowmax[r] = fmaxf(rowmax[r], v);
      }
#pragma unroll
    for (int d = 1; d < 16; d <<= 1)
#pragma unroll
      for (int r = 0; r < 4; ++r) rowmax[r] = fmaxf(rowmax[r], __shfl_xor(rowmax[r], d, 64));

    float alpha[4], rs[4];
#pragma unroll
    for (int r = 0; r < 4; ++r) {
      const float mnew = fmaxf(m_run[r], rowmax[r]);
      alpha[r] = expf(m_run[r] - mnew);
      m_run[r] = mnew;
      rs[r] = 0.f;
    }
#pragma unroll
    for (int cb = 0; cb < 4; ++cb)
#pragma unroll
      for (int r = 0; r < 4; ++r) {
        const float pij = expf(sc[cb][r] - m_run[r]);
        sc[cb][r] = pij;
        rs[r] += pij;
      }
#pragma unroll
    for (int d = 1; d < 16; d <<= 1)
#pragma unroll
      for (int r = 0; r < 4; ++r) rs[r] += __shfl_xor(rs[r], d, 64);
#pragma unroll
    for (int r = 0; r < 4; ++r) l_run[r] = l_run[r] * alpha[r] + rs[r];
#pragma unroll
    for (int d = 0; d < 4; ++d)
#pragma unroll
      for (int r = 0; r < 4; ++r) accO[d][r] *= alpha[r];

    // P -> LDS (per-wave region), then PV
#pragma unroll
    for (int cb = 0; cb < 4; ++cb)
#pragma unroll
      for (int r = 0; r < 4; ++r)
        Ps[w][(l4 * 4 + r) * 64 + cb * 16 + l15] = f2bf(sc[cb][r]);
#pragma unroll
    for (int ks2 = 0; ks2 < 2; ++ks2) {
      bf16x8 pa = *(const bf16x8*)&Ps[w][l15 * 64 + ks2 * 32 + l4 * 8];
#pragma unroll
      for (int df = 0; df < 4; ++df) {
        bf16x8 vb = *(const bf16x8*)&Vt[(df * 16 + l15) * 64 + ks2 * 32 + l4 * 8];
        accO[df] = __builtin_amdgcn_mfma_f32_16x16x32_bf16(pa, vb, accO[df], 0, 0, 0);
      }
    }
    __syncthreads();
  }

  // epilogue: normalize + write [b][s][h*64+d]
  const int b = bh >> 4, h = bh & 15;
  float inv[4];
#pragma unroll
  for (int r = 0; r < 4; ++r) inv[r] = 1.0f / l_run[r];
#pragma unroll
  for (int df = 0; df < 4; ++df)
#pragma unroll
    for (int r = 0; r < 4; ++r) {
      const int qrow = qt * 64 + w * 16 + l4 * 4 + r;
      Out[((size_t)(b * 2048 + qrow)) * 1024 + h * 64 + df * 16 + l15] = f2bf(accO[df][r] * inv[r]);
    }
}

// ---------------- launch ----------------
extern "C" void kernel_launch(void* const* d_in, const int* in_sizes, int n_in,
                              void* d_out, int out_size, void* d_ws, size_t ws_size,
                              hipStream_t stream) {
  const float* x    = (const float*)d_in[0];   // 4*2048*1024
  const float* wqkv = (const float*)d_in[1];   // 3072*1024
  const float* wo   = (const float*)d_in[2];   // 1024*1024
  const int*   pos  = (const int*)d_in[3];     // 2048
  float* out = (float*)d_out;

  char* ws = (char*)d_ws;
  unsigned short* xb    = (unsigned short*)(ws);                 // 16,777,216 B
  unsigned short* wqkvb = (unsigned short*)(ws + 16777216);      //  6,291,456 B
  unsigned short* wob   = (unsigned short*)(ws + 23068672);      //  2,097,152 B
  unsigned short* qkvb  = (unsigned short*)(ws + 25165824);      // 50,331,648 B
  unsigned short* Qr    = (unsigned short*)(ws + 75497472);      // 16,777,216 B
  unsigned short* Kr    = (unsigned short*)(ws + 92274688);      // 16,777,216 B
  unsigned short* Vr    = (unsigned short*)(ws + 109051904);     // 16,777,216 B -> 125,829,120 total
  unsigned short* att   = xb;  // reuse x_bf16 region for attention output

  cast_f32_bf16_k<<<2048, 256, 0, stream>>>(x, xb, 4 * 2048 * 1024);
  cast_f32_bf16_k<<<1024, 256, 0, stream>>>(wqkv, wqkvb, 3072 * 1024);
  cast_f32_bf16_k<<<512, 256, 0, stream>>>(wo, wob, 1024 * 1024);

  gemm_bf16_nt<unsigned short><<<dim3(24, 64), 256, 0, stream>>>(xb, wqkvb, qkvb, 8192, 3072, 1024);

  rope_repack<<<8192, 512, 0, stream>>>(qkvb, pos, Qr, Kr, Vr);

  attn_fwd<<<dim3(32, 64), 256, 0, stream>>>(Qr, Kr, Vr, att);

  gemm_bf16_nt<float><<<dim3(8, 64), 256, 0, stream>>>(att, wob, out, 8192, 1024, 1024);
}

// Round 4
// 290.622 us; speedup vs baseline: 1.7050x; 1.7050x over previous
//
#include <hip/hip_runtime.h>

// MHA forward: x[4,2048,1024] f32, W_QKV[3072,1024] f32, W_O[1024,1024] f32,
// pos[2048] i32 -> out[4,2048,1024] f32.
// Pipeline: cast->bf16 | QKV GEMM (MFMA) | RoPE repack | flash attn (MFMA) | out GEMM.
// R3: attn rewrite — XOR-swizzled Ks/Vt, padded Ps, conflict-free V writes,
//     2-phase prefetch (1 barrier/tile), XCD head-grouping, exp2-domain softmax.

typedef __attribute__((ext_vector_type(4))) float          f32x4;
typedef __attribute__((ext_vector_type(8))) __bf16         bf16x8;
typedef __attribute__((ext_vector_type(8))) unsigned short u16x8;
typedef __attribute__((ext_vector_type(4))) unsigned short u16x4;

__device__ __forceinline__ unsigned short f2bf(float f) {
  unsigned int u = __builtin_bit_cast(unsigned int, f);
  u = (u + 0x7fffu + ((u >> 16) & 1u)) >> 16;
  return (unsigned short)u;
}
__device__ __forceinline__ float bf2f(unsigned short b) {
  return __builtin_bit_cast(float, ((unsigned int)b) << 16);
}
__device__ __forceinline__ void gload_lds16(const void* g, void* l) {
  __builtin_amdgcn_global_load_lds((const __attribute__((address_space(1))) void*)g,
                                   (__attribute__((address_space(3))) void*)l, 16, 0, 0);
}

// ---------------- cast f32 -> bf16 ----------------
__global__ void cast_f32_bf16_k(const float* __restrict__ in, unsigned short* __restrict__ out, int n) {
  int i = (blockIdx.x * blockDim.x + threadIdx.x) * 4;
  const int stride = gridDim.x * blockDim.x * 4;
  for (; i < n; i += stride) {
    float4 v = *(const float4*)(in + i);
    u16x4 o = { f2bf(v.x), f2bf(v.y), f2bf(v.z), f2bf(v.w) };
    *(u16x4*)(out + i) = o;
  }
}

// ---------------- NT GEMM: C[M][N] = A[M][K] * B[N][K]^T ----------------
template <typename OutT>
__global__ __launch_bounds__(256) void gemm_bf16_nt(
    const unsigned short* __restrict__ A,
    const unsigned short* __restrict__ B,
    OutT* __restrict__ C,
    int M, int N, int K) {
  __shared__ unsigned short As[128 * 64];
  __shared__ unsigned short Bs[128 * 64];
  const int tid  = threadIdx.x;
  const int w    = tid >> 6;
  const int lane = tid & 63;
  const int l15  = lane & 15, l4 = lane >> 4;
  const int row0 = blockIdx.y * 128, col0 = blockIdx.x * 128;
  const int wrb  = (w >> 1) * 64, wcb = (w & 1) * 64;

  f32x4 acc[4][4];
  const f32x4 z = {0.f, 0.f, 0.f, 0.f};
#pragma unroll
  for (int m = 0; m < 4; ++m)
#pragma unroll
    for (int n = 0; n < 4; ++n) acc[m][n] = z;

  const int srow = w * 32 + (lane >> 3);
  const int scol = (lane & 7) * 8;

  for (int k0 = 0; k0 < K; k0 += 64) {
#pragma unroll
    for (int p = 0; p < 4; ++p) {
      gload_lds16(&A[(size_t)(row0 + srow + p * 8) * K + k0 + scol], &As[(w * 32 + p * 8) * 64]);
      gload_lds16(&B[(size_t)(col0 + srow + p * 8) * K + k0 + scol], &Bs[(w * 32 + p * 8) * 64]);
    }
    __syncthreads();
#pragma unroll
    for (int ks = 0; ks < 2; ++ks) {
      bf16x8 af[4], bfr[4];
#pragma unroll
      for (int m = 0; m < 4; ++m)
        af[m] = *(const bf16x8*)&As[(wrb + m * 16 + l15) * 64 + ks * 32 + l4 * 8];
#pragma unroll
      for (int n = 0; n < 4; ++n)
        bfr[n] = *(const bf16x8*)&Bs[(wcb + n * 16 + l15) * 64 + ks * 32 + l4 * 8];
#pragma unroll
      for (int m = 0; m < 4; ++m)
#pragma unroll
        for (int n = 0; n < 4; ++n)
          acc[m][n] = __builtin_amdgcn_mfma_f32_16x16x32_bf16(af[m], bfr[n], acc[m][n], 0, 0, 0);
    }
    __syncthreads();
  }
#pragma unroll
  for (int m = 0; m < 4; ++m) {
    const int row = row0 + wrb + m * 16 + l4 * 4;
#pragma unroll
    for (int n = 0; n < 4; ++n) {
      const int col = col0 + wcb + n * 16 + l15;
#pragma unroll
      for (int r = 0; r < 4; ++r) {
        float v = acc[m][n][r];
        if constexpr (sizeof(OutT) == 2)
          C[(size_t)(row + r) * N + col] = f2bf(v);
        else
          C[(size_t)(row + r) * N + col] = v;
      }
    }
  }
}

// ---------------- RoPE + repack qkv[B*S][3072] -> Q/K/V [B*H][S][64] ----------------
__global__ __launch_bounds__(512) void rope_repack(
    const unsigned short* __restrict__ qkv,
    const int* __restrict__ pos,
    unsigned short* __restrict__ Qr,
    unsigned short* __restrict__ Kr,
    unsigned short* __restrict__ Vr) {
  const int bs = blockIdx.x;
  const int b  = bs >> 11, s = bs & 2047;
  const int t  = threadIdx.x;
  const int h  = t >> 5, kk = t & 31;
  const float p    = (float)pos[s];
  const float freq = powf(10000.0f, -(float)kk * (1.0f / 32.0f));
  float sn, c;
  sincosf(p * freq, &sn, &c);
  const unsigned short* base = qkv + (size_t)bs * 3072;
  const size_t oidx = ((size_t)(b * 16 + h) * 2048 + s) * 64 + 2 * kk;
  float e = bf2f(base[h * 64 + 2 * kk]);
  float o = bf2f(base[h * 64 + 2 * kk + 1]);
  Qr[oidx]     = f2bf(c * e - sn * o);
  Qr[oidx + 1] = f2bf(sn * e + c * o);
  e = bf2f(base[1024 + h * 64 + 2 * kk]);
  o = bf2f(base[1024 + h * 64 + 2 * kk + 1]);
  Kr[oidx]     = f2bf(c * e - sn * o);
  Kr[oidx + 1] = f2bf(sn * e + c * o);
  Vr[oidx]     = base[2048 + h * 64 + 2 * kk];
  Vr[oidx + 1] = base[2048 + h * 64 + 2 * kk + 1];
}

// ---------------- causal flash attention (R3) ----------------
// grid 2048 blocks; 256 thr = 4 waves x 16 q-rows; KVBLK=64, double-buffered.
#define ATTN_SCL 0.18033688011112042f  // 0.125 * log2(e)

__global__ __launch_bounds__(256) void attn_fwd(
    const unsigned short* __restrict__ Qr,
    const unsigned short* __restrict__ Kr,
    const unsigned short* __restrict__ Vr,
    unsigned short* __restrict__ Out) {  // [B*S][1024]
  __shared__ unsigned short Ks[2][64 * 64];   // swizzled: byte ^= (row&7)<<4
  __shared__ unsigned short Vt[2][64 * 64];   // [d][key], swizzled same
  __shared__ unsigned short Ps[4][16 * 72];   // per-wave P, padded stride 72
  // XCD head-grouping: 8 heads per XCD (flat%8 selects head-group).
  const int flat = blockIdx.y * 32 + blockIdx.x;
  const int bh   = (flat & 7) * 8 + ((flat >> 3) & 7);
  const int qt   = flat >> 6;
  const int tid  = threadIdx.x, w = tid >> 6, lane = tid & 63;
  const int l15  = lane & 15, l4 = lane >> 4;
  const size_t hbase = (size_t)bh * 2048 * 64;

  // Q fragments (rows qt*64 + w*16 + l15)
  const int qrow_frag = qt * 64 + w * 16 + l15;
  bf16x8 qf[2];
  qf[0] = *(const bf16x8*)&Qr[hbase + (size_t)qrow_frag * 64 + l4 * 8];
  qf[1] = *(const bf16x8*)&Qr[hbase + (size_t)qrow_frag * 64 + 32 + l4 * 8];

  const f32x4 z = {0.f, 0.f, 0.f, 0.f};
  f32x4 accO[4];
#pragma unroll
  for (int d = 0; d < 4; ++d) accO[d] = z;
  float m_run[4], l_run[4];
#pragma unroll
  for (int r = 0; r < 4; ++r) { m_run[r] = -__builtin_inff(); l_run[r] = 0.f; }

  // --- staging helpers ---
  // K: LDS position (row, colByte cb') holds K[row][cb' ^ ((row&7)<<4)]
  const int krow_in = w * 16 + (lane >> 3);       // +p*8
  const int kcb0    = (lane & 7) * 16;            // linear dest byte col
  // V: thread handles key=lane, d-rows w*16..w*16+16
  const int vkey = lane, vd0 = w * 16;

#define STAGE_K(kt_, buf_)                                                              \
  {                                                                                     \
    _Pragma("unroll")                                                                   \
    for (int p = 0; p < 2; ++p) {                                                       \
      const int row = krow_in + p * 8;                                                  \
      const int scb = kcb0 ^ ((row & 7) << 4);                                          \
      gload_lds16(Kr + hbase + (size_t)((kt_) * 64 + row) * 64 + (scb >> 1),            \
                  &Ks[buf_][(w * 16 + p * 8) * 64]);                                    \
    }                                                                                   \
  }

#define WRITE_V(buf_, r0_, r1_)                                                         \
  {                                                                                     \
    _Pragma("unroll")                                                                   \
    for (int i = 0; i < 8; ++i) {                                                       \
      const int d = vd0 + i;                                                            \
      const int ba = (d << 7) + ((vkey * 2) ^ ((d & 7) << 4));                          \
      *(unsigned short*)((char*)&Vt[buf_][0] + ba) = (r0_)[i];                          \
    }                                                                                   \
    _Pragma("unroll")                                                                   \
    for (int i = 0; i < 8; ++i) {                                                       \
      const int d = vd0 + 8 + i;                                                        \
      const int ba = (d << 7) + ((vkey * 2) ^ ((d & 7) << 4));                          \
      *(unsigned short*)((char*)&Vt[buf_][0] + ba) = (r1_)[i];                          \
    }                                                                                   \
  }

  // prologue: stage tile 0 into buf 0
  {
    STAGE_K(0, 0);
    const unsigned short* gv = Vr + hbase + (size_t)vkey * 64 + vd0;
    u16x8 pv0 = *(const u16x8*)gv;
    u16x8 pv1 = *(const u16x8*)(gv + 8);
    WRITE_V(0, pv0, pv1);
  }
  __syncthreads();

  for (int kt = 0; kt <= qt; ++kt) {
    const int cbuf = kt & 1, nbuf = cbuf ^ 1;
    const bool pre = (kt < qt);
    u16x8 nv0, nv1;
    if (pre) {
      STAGE_K(kt + 1, nbuf);
      const unsigned short* gv = Vr + hbase + (size_t)((kt + 1) * 64 + vkey) * 64 + vd0;
      nv0 = *(const u16x8*)gv;
      nv1 = *(const u16x8*)(gv + 8);
    }

    // S = Q K^T  (swizzled K reads)
    f32x4 sc[4];
#pragma unroll
    for (int cb = 0; cb < 4; ++cb) sc[cb] = z;
#pragma unroll
    for (int ks = 0; ks < 2; ++ks)
#pragma unroll
      for (int cb = 0; cb < 4; ++cb) {
        const int row = cb * 16 + l15;
        const int off = (row << 7) + ((ks * 64 + l4 * 16) ^ ((l15 & 7) << 4));
        bf16x8 kb = *(const bf16x8*)((const char*)&Ks[cbuf][0] + off);
        sc[cb] = __builtin_amdgcn_mfma_f32_16x16x32_bf16(qf[ks], kb, sc[cb], 0, 0, 0);
      }

    // scale (exp2 domain) + causal mask + row max
    const bool diag = (kt == qt);
    float rowmax[4];
#pragma unroll
    for (int r = 0; r < 4; ++r) rowmax[r] = -__builtin_inff();
#pragma unroll
    for (int cb = 0; cb < 4; ++cb)
#pragma unroll
      for (int r = 0; r < 4; ++r) {
        float v = sc[cb][r] * ATTN_SCL;
        if (diag) {
          const int key = cb * 16 + l15;
          const int qr  = w * 16 + l4 * 4 + r;
          if (key > qr) v = -__builtin_inff();
        }
        sc[cb][r] = v;
        rowmax[r] = fmaxf(rowmax[r], v);
      }
#pragma unroll
    for (int d = 1; d < 16; d <<= 1)
#pragma unroll
      for (int r = 0; r < 4; ++r) rowmax[r] = fmaxf(rowmax[r], __shfl_xor(rowmax[r], d, 64));

    float alpha[4], rs[4];
#pragma unroll
    for (int r = 0; r < 4; ++r) {
      const float mnew = fmaxf(m_run[r], rowmax[r]);
      alpha[r] = exp2f(m_run[r] - mnew);
      m_run[r] = mnew;
      rs[r] = 0.f;
    }
#pragma unroll
    for (int cb = 0; cb < 4; ++cb)
#pragma unroll
      for (int r = 0; r < 4; ++r) {
        const float pij = exp2f(sc[cb][r] - m_run[r]);
        sc[cb][r] = pij;
        rs[r] += pij;
      }
#pragma unroll
    for (int d = 1; d < 16; d <<= 1)
#pragma unroll
      for (int r = 0; r < 4; ++r) rs[r] += __shfl_xor(rs[r], d, 64);
#pragma unroll
    for (int r = 0; r < 4; ++r) l_run[r] = l_run[r] * alpha[r] + rs[r];
#pragma unroll
    for (int d = 0; d < 4; ++d)
#pragma unroll
      for (int r = 0; r < 4; ++r) accO[d][r] *= alpha[r];

    // P -> per-wave LDS (padded), then PV (swizzled V reads)
#pragma unroll
    for (int cb = 0; cb < 4; ++cb)
#pragma unroll
      for (int r = 0; r < 4; ++r)
        Ps[w][(l4 * 4 + r) * 72 + cb * 16 + l15] = f2bf(sc[cb][r]);
#pragma unroll
    for (int ks2 = 0; ks2 < 2; ++ks2) {
      bf16x8 pa = *(const bf16x8*)&Ps[w][l15 * 72 + ks2 * 32 + l4 * 8];
#pragma unroll
      for (int df = 0; df < 4; ++df) {
        const int row = df * 16 + l15;
        const int off = (row << 7) + ((ks2 * 64 + l4 * 16) ^ ((l15 & 7) << 4));
        bf16x8 vb = *(const bf16x8*)((const char*)&Vt[cbuf][0] + off);
        accO[df] = __builtin_amdgcn_mfma_f32_16x16x32_bf16(pa, vb, accO[df], 0, 0, 0);
      }
    }

    if (pre) WRITE_V(nbuf, nv0, nv1);  // compiler waits vmcnt on nv use
    __syncthreads();
  }

  // epilogue: normalize + write [b][s][h*64+d]
  const int b = bh >> 4, h = bh & 15;
  float inv[4];
#pragma unroll
  for (int r = 0; r < 4; ++r) inv[r] = 1.0f / l_run[r];
#pragma unroll
  for (int df = 0; df < 4; ++df)
#pragma unroll
    for (int r = 0; r < 4; ++r) {
      const int qrow = qt * 64 + w * 16 + l4 * 4 + r;
      Out[((size_t)(b * 2048 + qrow)) * 1024 + h * 64 + df * 16 + l15] = f2bf(accO[df][r] * inv[r]);
    }
}

// ---------------- launch ----------------
extern "C" void kernel_launch(void* const* d_in, const int* in_sizes, int n_in,
                              void* d_out, int out_size, void* d_ws, size_t ws_size,
                              hipStream_t stream) {
  const float* x    = (const float*)d_in[0];
  const float* wqkv = (const float*)d_in[1];
  const float* wo   = (const float*)d_in[2];
  const int*   pos  = (const int*)d_in[3];
  float* out = (float*)d_out;

  char* ws = (char*)d_ws;
  unsigned short* xb    = (unsigned short*)(ws);
  unsigned short* wqkvb = (unsigned short*)(ws + 16777216);
  unsigned short* wob   = (unsigned short*)(ws + 23068672);
  unsigned short* qkvb  = (unsigned short*)(ws + 25165824);
  unsigned short* Qr    = (unsigned short*)(ws + 75497472);
  unsigned short* Kr    = (unsigned short*)(ws + 92274688);
  unsigned short* Vr    = (unsigned short*)(ws + 109051904);
  unsigned short* att   = xb;

  cast_f32_bf16_k<<<2048, 256, 0, stream>>>(x, xb, 4 * 2048 * 1024);
  cast_f32_bf16_k<<<1024, 256, 0, stream>>>(wqkv, wqkvb, 3072 * 1024);
  cast_f32_bf16_k<<<512, 256, 0, stream>>>(wo, wob, 1024 * 1024);

  gemm_bf16_nt<unsigned short><<<dim3(24, 64), 256, 0, stream>>>(xb, wqkvb, qkvb, 8192, 3072, 1024);

  rope_repack<<<8192, 512, 0, stream>>>(qkvb, pos, Qr, Kr, Vr);

  attn_fwd<<<dim3(32, 64), 256, 0, stream>>>(Qr, Kr, Vr, att);

  gemm_bf16_nt<float><<<dim3(8, 64), 256, 0, stream>>>(att, wob, out, 8192, 1024, 1024);
}